// Round 1
// baseline (3680.505 us; speedup 1.0000x reference)
//
#include <hip/hip_runtime.h>

#define NN 8192
#define ALPHA  0.4f
#define THETA1 0.24f   // alpha*(1-alpha)

using bf16x8 = __attribute__((ext_vector_type(8))) short;
using f32x4  = __attribute__((ext_vector_type(4))) float;

__device__ __forceinline__ unsigned short f2bf(float f) {
    unsigned u = __float_as_uint(f);
    u += 0x7fffu + ((u >> 16) & 1u);      // round-to-nearest-even
    return (unsigned short)(u >> 16);
}
__device__ __forceinline__ float bf2f(unsigned short h) {
    return __uint_as_float(((unsigned)h) << 16);
}

// async global->LDS, 16B per lane; lds ptr must be wave-uniform
#define GLD16(g, l_) __builtin_amdgcn_global_load_lds( \
    (const __attribute__((address_space(1))) void*)(g), \
    (__attribute__((address_space(3))) void*)(l_), 16, 0, 0)

// ---------------------------------------------------------------- degree
__global__ __launch_bounds__(256) void deg_kernel(const int* __restrict__ col,
                                                  float* __restrict__ deg, int E) {
    int e = blockIdx.x * 256 + threadIdx.x;
    if (e < E) {
        unsigned c = (unsigned)col[e];
        if (c < NN) atomicAdd(&deg[c], 1.0f);
    }
}

// ------------------------------------------------------- normalized scatter
__global__ __launch_bounds__(256) void scatter_kernel(const int* __restrict__ row,
                                                      const int* __restrict__ col,
                                                      const float* __restrict__ attr,
                                                      const float* __restrict__ deg,
                                                      float* __restrict__ Af, int E) {
    int e = blockIdx.x * 256 + threadIdx.x;
    if (e < E) {
        unsigned r = (unsigned)row[e], c = (unsigned)col[e];
        if (r < NN && c < NN) {
            float v = rsqrtf(deg[r]) * attr[e] * rsqrtf(deg[c]);
            atomicAdd(&Af[(size_t)r * NN + c], v);
        }
    }
}

// ---------------------------------------------------------- f32 -> bf16
__global__ __launch_bounds__(256) void convert_kernel(const float* __restrict__ in,
                                                      unsigned short* __restrict__ out) {
    size_t i = ((size_t)blockIdx.x * 256 + threadIdx.x) * 4;
    float4 v = *(const float4*)&in[i];
    unsigned short o[4] = {f2bf(v.x), f2bf(v.y), f2bf(v.z), f2bf(v.w)};
    *(uint2*)&out[i] = *(const uint2*)o;
}

// ------------------------------------------------------ bf16 transpose 64x64
__global__ __launch_bounds__(256) void transpose_kernel(const unsigned short* __restrict__ in,
                                                        unsigned short* __restrict__ out) {
    __shared__ unsigned short tile[64][72];   // +8 pad breaks bank conflicts
    int bx = blockIdx.x & 127;                // col tile
    int by = blockIdx.x >> 7;                 // row tile
    size_t r0 = (size_t)by * 64, c0 = (size_t)bx * 64;
    int t = threadIdx.x;
#pragma unroll
    for (int p = 0; p < 2; ++p) {
        int idx = p * 256 + t;
        int r = idx >> 3, c = (idx & 7) * 8;
        *(uint4*)&tile[r][c] = *(const uint4*)&in[(r0 + r) * NN + c0 + c];
    }
    __syncthreads();
#pragma unroll
    for (int p = 0; p < 2; ++p) {
        int idx = p * 256 + t;
        int r = idx >> 3, c = (idx & 7) * 8;
        alignas(16) unsigned short tmp[8];
#pragma unroll
        for (int j = 0; j < 8; ++j) tmp[j] = tile[c + j][r];
        *(uint4*)&out[(c0 + r) * NN + r0 + c] = *(const uint4*)tmp;
    }
}

// ------------------------------------------------------------------- GEMM
// C = X * Y where YT is Y transposed (both row-major bf16, NN x NN).
// FINAL=0: write bf16 C to OutBf.   FINAL=1: P = THETA1*(A + A2 + C) + ALPHA*I.
template <int FINAL>
__global__ __launch_bounds__(256) void gemm_kernel(const unsigned short* __restrict__ X,
                                                   const unsigned short* __restrict__ YT,
                                                   unsigned short* __restrict__ OutBf,
                                                   float* __restrict__ P,
                                                   const unsigned short* __restrict__ Abf,
                                                   const unsigned short* __restrict__ A2bf) {
    __shared__ unsigned short lx[128 * 32];
    __shared__ unsigned short ly[128 * 32];

    // XCD-aware bijective swizzle: 4096 wgs, 8 XCDs, 512 per XCD
    int bid  = blockIdx.x;
    int tile = (bid & 7) * 512 + (bid >> 3);
    int tm = tile >> 6, tn = tile & 63;
    size_t m0 = (size_t)tm * 128, n0 = (size_t)tn * 128;

    int t = threadIdx.x;
    int l = t & 63, w = t >> 6;
    int lane16 = l & 15, hi = l >> 4;
    int wr = w >> 1, wc = w & 1;

    f32x4 acc[4][4] = {};

    // staging geometry: pass p covers rows p*64 + (t>>2), cols (t&3)*8 .. +8
    int sr = t >> 2;
    int sc = (t & 3) * 8;
    const unsigned short* gx0 = X  + (m0 + sr) * NN + sc;
    const unsigned short* gx1 = gx0 + (size_t)64 * NN;
    const unsigned short* gy0 = YT + (n0 + sr) * NN + sc;
    const unsigned short* gy1 = gy0 + (size_t)64 * NN;
    unsigned short* ldx0 = lx + w * 512;
    unsigned short* ldx1 = lx + 2048 + w * 512;
    unsigned short* ldy0 = ly + w * 512;
    unsigned short* ldy1 = ly + 2048 + w * 512;

    for (int k0 = 0; k0 < NN; k0 += 32) {
        GLD16(gx0 + k0, ldx0);
        GLD16(gx1 + k0, ldx1);
        GLD16(gy0 + k0, ldy0);
        GLD16(gy1 + k0, ldy1);
        __syncthreads();

        bf16x8 af[4], bfr[4];
#pragma unroll
        for (int m = 0; m < 4; ++m)
            af[m] = *(const bf16x8*)&lx[(wr * 64 + m * 16 + lane16) * 32 + hi * 8];
#pragma unroll
        for (int n = 0; n < 4; ++n)
            bfr[n] = *(const bf16x8*)&ly[(wc * 64 + n * 16 + lane16) * 32 + hi * 8];
#pragma unroll
        for (int m = 0; m < 4; ++m)
#pragma unroll
            for (int n = 0; n < 4; ++n)
                acc[m][n] = __builtin_amdgcn_mfma_f32_16x16x32_bf16(af[m], bfr[n], acc[m][n], 0, 0, 0);
        __syncthreads();
    }

    // epilogue: C/D layout col = lane&15, row = (lane>>4)*4 + q  [verified m89/m91]
    size_t baseR = m0 + (size_t)wr * 64;
    size_t baseC = n0 + (size_t)wc * 64 + lane16;
#pragma unroll
    for (int m = 0; m < 4; ++m) {
#pragma unroll
        for (int n = 0; n < 4; ++n) {
#pragma unroll
            for (int q = 0; q < 4; ++q) {
                size_t gr = baseR + m * 16 + hi * 4 + q;
                size_t gc = baseC + n * 16;
                size_t idx = gr * NN + gc;
                if (FINAL) {
                    float v = THETA1 * (bf2f(Abf[idx]) + bf2f(A2bf[idx]) + acc[m][n][q]);
                    if (gr == gc) v += ALPHA;
                    P[idx] = v;
                } else {
                    OutBf[idx] = f2bf(acc[m][n][q]);
                }
            }
        }
    }
}

// ------------------------------------------------------------------ launch
extern "C" void kernel_launch(void* const* d_in, const int* in_sizes, int n_in,
                              void* d_out, int out_size, void* d_ws, size_t ws_size,
                              hipStream_t stream) {
    const float* attr = (const float*)d_in[1];
    const int*   eidx = (const int*)d_in[2];
    int E = in_sizes[1];
    const int* row = eidx;
    const int* col = eidx + E;

    const size_t MAT = (size_t)NN * NN;          // elements
    unsigned short* Abf   = (unsigned short*)d_ws;
    unsigned short* ATbf  = Abf  + MAT;
    unsigned short* A2bf  = ATbf + MAT;
    unsigned short* A2Tbf = A2bf + MAT;
    float*          deg   = (float*)(A2Tbf + MAT);

    size_t need = MAT * 2 * 4 + NN * sizeof(float);
    if (ws_size < need) return;                  // workspace too small -> visible failure

    float* Af = (float*)d_out;                   // f32 A staging lives in d_out
    float* P  = (float*)d_out;                   // final output overwrites it

    hipMemsetAsync(d_out, 0, MAT * sizeof(float), stream);
    hipMemsetAsync(deg, 0, NN * sizeof(float), stream);

    int eb = (E + 255) / 256;
    deg_kernel<<<eb, 256, 0, stream>>>(col, deg, E);
    scatter_kernel<<<eb, 256, 0, stream>>>(row, col, attr, deg, Af, E);
    convert_kernel<<<(int)(MAT / 1024), 256, 0, stream>>>(Af, Abf);
    transpose_kernel<<<16384, 256, 0, stream>>>(Abf, ATbf);
    gemm_kernel<0><<<4096, 256, 0, stream>>>(Abf, ATbf, A2bf, nullptr, nullptr, nullptr);
    transpose_kernel<<<16384, 256, 0, stream>>>(A2bf, A2Tbf);
    gemm_kernel<1><<<4096, 256, 0, stream>>>(Abf, A2Tbf, nullptr, P, Abf, A2bf);
}

// Round 3
// 1916.722 us; speedup vs baseline: 1.9202x; 1.9202x over previous
//
#include <hip/hip_runtime.h>

#define NN 8192
#define ALPHA  0.4f
#define THETA1 0.24f   // alpha*(1-alpha)

__device__ __forceinline__ unsigned short f2bf(float f) {
    unsigned u = __float_as_uint(f);
    u += 0x7fffu + ((u >> 16) & 1u);      // round-to-nearest-even
    return (unsigned short)(u >> 16);
}

// ------------------------------------------------- degree + row counts
__global__ __launch_bounds__(256) void deg_count_kernel(const int* __restrict__ row,
                                                        const int* __restrict__ col,
                                                        float* __restrict__ deg,
                                                        int* __restrict__ cnt, int E) {
    int e = blockIdx.x * 256 + threadIdx.x;
    if (e >= E) return;
    unsigned r = (unsigned)row[e], c = (unsigned)col[e];
    if (r < NN && c < NN) {
        atomicAdd(&deg[c], 1.0f);     // unweighted in-degree on col (reference semantics)
        atomicAdd(&cnt[r], 1);        // CSR row count
    }
}

// ------------------------------------------------- exclusive scan (8192, one block)
__global__ __launch_bounds__(256) void scan_kernel(const int* __restrict__ cnt,
                                                   int* __restrict__ rowptr,
                                                   int* __restrict__ cursor) {
    __shared__ int sums[257];
    int t = threadIdx.x;
    int base = t * 32;
    int s = 0;
    for (int j = 0; j < 32; ++j) s += cnt[base + j];
    sums[t] = s;
    __syncthreads();
    if (t == 0) {
        int run = 0;
        for (int i = 0; i < 256; ++i) { int x = sums[i]; sums[i] = run; run += x; }
        sums[256] = run;
    }
    __syncthreads();
    int run = sums[t];
    for (int j = 0; j < 32; ++j) {
        rowptr[base + j] = run;
        cursor[base + j] = run;
        run += cnt[base + j];
    }
    if (t == 255) rowptr[NN] = sums[256];
}

// ---------------------------------- normalized values -> dense f32 A + CSR fill
__global__ __launch_bounds__(256) void fill_kernel(const int* __restrict__ row,
                                                   const int* __restrict__ col,
                                                   const float* __restrict__ attr,
                                                   const float* __restrict__ deg,
                                                   int* __restrict__ cursor,
                                                   int2* __restrict__ ecsr,
                                                   float* __restrict__ Af, int E) {
    int e = blockIdx.x * 256 + threadIdx.x;
    if (e >= E) return;
    unsigned r = (unsigned)row[e], c = (unsigned)col[e];
    if (r < NN && c < NN) {
        float v = rsqrtf(deg[r]) * attr[e] * rsqrtf(deg[c]);
        atomicAdd(&Af[(size_t)r * NN + c], v);             // dense A (coalesce semantics)
        int pos = atomicAdd(&cursor[r], 1);
        ecsr[pos] = make_int2((int)c, __float_as_int(v));  // CSR entry (col, val)
    }
}

// ------------------------------------------------- f32 -> bf16
__global__ __launch_bounds__(256) void convert_kernel(const float* __restrict__ in,
                                                      unsigned short* __restrict__ out) {
    size_t i = ((size_t)blockIdx.x * 256 + threadIdx.x) * 4;
    float4 v = *(const float4*)&in[i];
    unsigned short o[4] = {f2bf(v.x), f2bf(v.y), f2bf(v.z), f2bf(v.w)};
    *(uint2*)&out[i] = *(const uint2*)o;
}

// ------------------------------------------------- SpMM: Out = A(sparse) * S(dense bf16)
// One wave per (output row, 256-col slice). blockIdx.x = row group (fast, 2048),
// blockIdx.y = col block (slow, 32) -> resident cohort shares a 4 MB source window in L2.
// FINAL=0: write bf16 A2.  FINAL=1: P = THETA1*(A + A2 + acc) + ALPHA*I  (f32).
template <int FINAL>
__global__ __launch_bounds__(256) void spmm_kernel(const int* __restrict__ rowptr,
                                                   const int2* __restrict__ ecsr,
                                                   const unsigned short* __restrict__ S,
                                                   unsigned short* __restrict__ OutBf,
                                                   float* __restrict__ P,
                                                   const unsigned short* __restrict__ Abf,
                                                   const unsigned short* __restrict__ A2bf) {
    int lane = threadIdx.x & 63;
    int wave = threadIdx.x >> 6;
    int r  = blockIdx.x * 4 + wave;
    int c0 = blockIdx.y << 8;                        // col block * 256
    int e0 = __builtin_amdgcn_readfirstlane(rowptr[r]);
    int e1 = __builtin_amdgcn_readfirstlane(rowptr[r + 1]);
    const unsigned short* Sc = S + c0 + lane * 4;    // 4 bf16 per lane = 8 B gather
    float a0 = 0.f, a1 = 0.f, a2 = 0.f, a3 = 0.f;

#define GATHER(kv) (*(const uint2*)(Sc + ((size_t)(unsigned)(kv).x << 13)))
#define ACCUM(raw, vv) { a0 = fmaf(vv, __uint_as_float((raw).x << 16), a0);          \
                         a1 = fmaf(vv, __uint_as_float((raw).x & 0xffff0000u), a1);  \
                         a2 = fmaf(vv, __uint_as_float((raw).y << 16), a2);          \
                         a3 = fmaf(vv, __uint_as_float((raw).y & 0xffff0000u), a3); }
    int e = e0;
    for (; e + 4 <= e1; e += 4) {                    // 4 gathers in flight
        int2 kv0 = ecsr[e],     kv1 = ecsr[e + 1];
        int2 kv2 = ecsr[e + 2], kv3 = ecsr[e + 3];
        uint2 g0 = GATHER(kv0); uint2 g1 = GATHER(kv1);
        uint2 g2 = GATHER(kv2); uint2 g3 = GATHER(kv3);
        ACCUM(g0, __int_as_float(kv0.y)); ACCUM(g1, __int_as_float(kv1.y));
        ACCUM(g2, __int_as_float(kv2.y)); ACCUM(g3, __int_as_float(kv3.y));
    }
    for (; e < e1; ++e) {
        int2 kv = ecsr[e];
        uint2 g = GATHER(kv);
        ACCUM(g, __int_as_float(kv.y));
    }
#undef GATHER
#undef ACCUM

    size_t idx = (size_t)r * NN + c0 + lane * 4;
    if (FINAL) {
        uint2 ab = *(const uint2*)&Abf[idx];
        uint2 bb = *(const uint2*)&A2bf[idx];
        float o0 = THETA1 * (__uint_as_float(ab.x << 16) + __uint_as_float(bb.x << 16) + a0);
        float o1 = THETA1 * (__uint_as_float(ab.x & 0xffff0000u) + __uint_as_float(bb.x & 0xffff0000u) + a1);
        float o2 = THETA1 * (__uint_as_float(ab.y << 16) + __uint_as_float(bb.y << 16) + a2);
        float o3 = THETA1 * (__uint_as_float(ab.y & 0xffff0000u) + __uint_as_float(bb.y & 0xffff0000u) + a3);
        int d = r - (c0 + lane * 4);
        if (d == 0) o0 += ALPHA;
        else if (d == 1) o1 += ALPHA;
        else if (d == 2) o2 += ALPHA;
        else if (d == 3) o3 += ALPHA;
        float4 o = make_float4(o0, o1, o2, o3);
        *(float4*)&P[idx] = o;
    } else {
        unsigned short h[4] = { f2bf(a0), f2bf(a1), f2bf(a2), f2bf(a3) };
        *(uint2*)&OutBf[idx] = *(const uint2*)h;
    }
}

// ------------------------------------------------------------------ launch
extern "C" void kernel_launch(void* const* d_in, const int* in_sizes, int n_in,
                              void* d_out, int out_size, void* d_ws, size_t ws_size,
                              hipStream_t stream) {
    const float* attr = (const float*)d_in[1];
    const int*   eidx = (const int*)d_in[2];
    int E = in_sizes[1];
    const int* row = eidx;
    const int* col = eidx + E;

    const size_t MAT = (size_t)NN * NN;
    unsigned short* Abf  = (unsigned short*)d_ws;            // 128 MB
    unsigned short* A2bf = Abf + MAT;                        // 128 MB
    float* deg   = (float*)(A2bf + MAT);                     // 32 KB
    int*   cnt    = (int*)(deg + NN);                        // 32 KB
    int*   rowptr = cnt + NN;                                // (NN+2)*4 (pad keeps 8B align)
    int*   cursor = rowptr + NN + 2;                         // 32 KB
    int2*  ecsr   = (int2*)(cursor + NN);                    // E*8 B

    size_t need = MAT * 2 * sizeof(unsigned short)
                + (size_t)(NN * 3 + NN + 2) * sizeof(int)
                + (size_t)E * sizeof(int2);
    if (ws_size < need) return;

    float* Af = (float*)d_out;     // f32 A staging in d_out (dead after convert)
    float* P  = (float*)d_out;     // final output overwrites it

    hipMemsetAsync(d_out, 0, MAT * sizeof(float), stream);
    hipMemsetAsync(deg, 0, NN * sizeof(float), stream);
    hipMemsetAsync(cnt, 0, NN * sizeof(int), stream);

    int eb = (E + 255) / 256;
    deg_count_kernel<<<eb, 256, 0, stream>>>(row, col, deg, cnt, E);
    scan_kernel<<<1, 256, 0, stream>>>(cnt, rowptr, cursor);
    fill_kernel<<<eb, 256, 0, stream>>>(row, col, attr, deg, cursor, ecsr, Af, E);
    convert_kernel<<<(int)(MAT / 1024), 256, 0, stream>>>(Af, Abf);

    dim3 sgrid(NN / 4, 32);
    spmm_kernel<0><<<sgrid, 256, 0, stream>>>(rowptr, ecsr, Abf, A2bf, nullptr, nullptr, nullptr);
    spmm_kernel<1><<<sgrid, 256, 0, stream>>>(rowptr, ecsr, A2bf, nullptr, P, Abf, A2bf);
}

// Round 5
// 1697.651 us; speedup vs baseline: 2.1680x; 1.1290x over previous
//
#include <hip/hip_runtime.h>

#define NN 8192
#define ALPHA  0.4f
#define THETA1 0.24f   // alpha*(1-alpha)

typedef float    f32x2 __attribute__((ext_vector_type(2)));
typedef float    f32x4 __attribute__((ext_vector_type(4)));
typedef unsigned u32x2 __attribute__((ext_vector_type(2)));

__device__ __forceinline__ unsigned short f2bf(float f) {
    unsigned u = __float_as_uint(f);
    u += 0x7fffu + ((u >> 16) & 1u);      // round-to-nearest-even
    return (unsigned short)(u >> 16);
}

// ------------------------------------------------- degree + row counts
__global__ __launch_bounds__(256) void deg_count_kernel(const int* __restrict__ row,
                                                        const int* __restrict__ col,
                                                        float* __restrict__ deg,
                                                        int* __restrict__ cnt, int E) {
    int e = blockIdx.x * 256 + threadIdx.x;
    if (e >= E) return;
    unsigned r = (unsigned)row[e], c = (unsigned)col[e];
    if (r < NN && c < NN) {
        atomicAdd(&deg[c], 1.0f);     // unweighted in-degree on col (reference semantics)
        atomicAdd(&cnt[r], 1);        // CSR row count
    }
}

// ------------------------------------------------- exclusive scan (8192, one block)
__global__ __launch_bounds__(256) void scan_kernel(const int* __restrict__ cnt,
                                                   int* __restrict__ rowptr,
                                                   int* __restrict__ cursor) {
    __shared__ int sums[257];
    int t = threadIdx.x;
    int base = t * 32;
    int s = 0;
    for (int j = 0; j < 32; ++j) s += cnt[base + j];
    sums[t] = s;
    __syncthreads();
    if (t == 0) {
        int run = 0;
        for (int i = 0; i < 256; ++i) { int x = sums[i]; sums[i] = run; run += x; }
        sums[256] = run;
    }
    __syncthreads();
    int run = sums[t];
    for (int j = 0; j < 32; ++j) {
        rowptr[base + j] = run;
        cursor[base + j] = run;
        run += cnt[base + j];
    }
    if (t == 255) rowptr[NN] = sums[256];
}

// ----------------- normalized values -> dense f32 A + packed CSR fill
// packed entry: bits 0-12 = col, bits 16-31 = bf16(value)
__global__ __launch_bounds__(256) void fill_kernel(const int* __restrict__ row,
                                                   const int* __restrict__ col,
                                                   const float* __restrict__ attr,
                                                   const float* __restrict__ deg,
                                                   int* __restrict__ cursor,
                                                   unsigned* __restrict__ epk,
                                                   float* __restrict__ Af, int E) {
    int e = blockIdx.x * 256 + threadIdx.x;
    if (e >= E) return;
    unsigned r = (unsigned)row[e], c = (unsigned)col[e];
    if (r < NN && c < NN) {
        float v = rsqrtf(deg[r]) * attr[e] * rsqrtf(deg[c]);
        atomicAdd(&Af[(size_t)r * NN + c], v);             // dense A (coalesce semantics)
        int pos = atomicAdd(&cursor[r], 1);
        epk[pos] = ((unsigned)f2bf(v) << 16) | c;
    }
}

// ------------------------------------------------- f32 -> bf16 (streaming, NT)
__global__ __launch_bounds__(256) void convert_kernel(const float* __restrict__ in,
                                                      unsigned short* __restrict__ out) {
    size_t i = ((size_t)blockIdx.x * 256 + threadIdx.x) * 4;
    f32x4 v = __builtin_nontemporal_load((const f32x4*)&in[i]);
    unsigned lo = ((unsigned)f2bf(v.y) << 16) | (unsigned)f2bf(v.x);
    unsigned hi = ((unsigned)f2bf(v.w) << 16) | (unsigned)f2bf(v.z);
    u32x2 pk = {lo, hi};
    __builtin_nontemporal_store(pk, (u32x2*)&out[i]);
}

// ------------------------------------------------- SpMM: Out = A(sparse) * S(dense bf16)
// 64 col-slabs of 128 cols. XCD-dedicated slabs: xcd = bid&7 owns slabs
// [xcd*8, xcd*8+8) -> each 2 MB source window is fetched into exactly ONE L2.
// One wave per (output row, slab). Outputs via nontemporal stores (no L2/L3 pollution).
// FINAL=0: write bf16 A2.  FINAL=1: P = THETA1*(A + A2 + acc) + ALPHA*I  (f32).
template <int FINAL>
__global__ __launch_bounds__(256) void spmm_kernel(const int* __restrict__ rowptr,
                                                   const unsigned* __restrict__ epk,
                                                   const unsigned short* __restrict__ S,
                                                   unsigned short* __restrict__ OutBf,
                                                   float* __restrict__ P,
                                                   const unsigned short* __restrict__ Abf,
                                                   const unsigned short* __restrict__ A2bf) {
    int lane = threadIdx.x & 63;
    int wave = threadIdx.x >> 6;
    unsigned bid   = blockIdx.x;
    unsigned xcd   = bid & 7u;
    unsigned local = bid >> 3;                   // [0, 16384)
    unsigned slab  = (xcd << 3) | (local >> 11); // [0, 64), 8 slabs per XCD
    unsigned rg    = local & 2047u;              // row group [0, 2048)
    int r  = (int)(rg * 4 + wave);
    int c0 = (int)(slab << 7);                   // 128-col slab
    int e0 = __builtin_amdgcn_readfirstlane(rowptr[r]);
    int e1 = __builtin_amdgcn_readfirstlane(rowptr[r + 1]);
    const unsigned short* Sc = S + c0 + (lane << 1);   // 2 bf16 per lane = 4 B gather
    float a0 = 0.f, a1 = 0.f;

#define GATHER(u) (*(const unsigned*)(Sc + (((size_t)((u) & 0x1fffu)) << 13)))
#define ACCUM(g, u) { float vv = __uint_as_float((u) & 0xffff0000u);        \
                      a0 = fmaf(vv, __uint_as_float((g) << 16), a0);        \
                      a1 = fmaf(vv, __uint_as_float((g) & 0xffff0000u), a1); }
    int e = e0;
    for (; e + 8 <= e1; e += 8) {                // 8 gathers in flight
        unsigned u0 = epk[e],     u1 = epk[e + 1];
        unsigned u2 = epk[e + 2], u3 = epk[e + 3];
        unsigned u4 = epk[e + 4], u5 = epk[e + 5];
        unsigned u6 = epk[e + 6], u7 = epk[e + 7];
        unsigned g0 = GATHER(u0), g1 = GATHER(u1), g2 = GATHER(u2), g3 = GATHER(u3);
        unsigned g4 = GATHER(u4), g5 = GATHER(u5), g6 = GATHER(u6), g7 = GATHER(u7);
        ACCUM(g0, u0); ACCUM(g1, u1); ACCUM(g2, u2); ACCUM(g3, u3);
        ACCUM(g4, u4); ACCUM(g5, u5); ACCUM(g6, u6); ACCUM(g7, u7);
    }
    for (; e < e1; ++e) {
        unsigned u = epk[e];
        unsigned g = GATHER(u);
        ACCUM(g, u);
    }
#undef GATHER
#undef ACCUM

    size_t idx = (size_t)r * NN + c0 + (lane << 1);
    if (FINAL) {
        unsigned ab = __builtin_nontemporal_load((const unsigned*)(Abf + idx));
        unsigned bb = __builtin_nontemporal_load((const unsigned*)(A2bf + idx));
        float o0 = THETA1 * (__uint_as_float(ab << 16) + __uint_as_float(bb << 16) + a0);
        float o1 = THETA1 * (__uint_as_float(ab & 0xffff0000u) + __uint_as_float(bb & 0xffff0000u) + a1);
        int d = r - (c0 + (lane << 1));
        if (d == 0) o0 += ALPHA;
        else if (d == 1) o1 += ALPHA;
        f32x2 o = {o0, o1};
        __builtin_nontemporal_store(o, (f32x2*)(P + idx));
    } else {
        unsigned pk = ((unsigned)f2bf(a1) << 16) | (unsigned)f2bf(a0);
        __builtin_nontemporal_store(pk, (unsigned*)(OutBf + idx));
    }
}

// ------------------------------------------------------------------ launch
extern "C" void kernel_launch(void* const* d_in, const int* in_sizes, int n_in,
                              void* d_out, int out_size, void* d_ws, size_t ws_size,
                              hipStream_t stream) {
    const float* attr = (const float*)d_in[1];
    const int*   eidx = (const int*)d_in[2];
    int E = in_sizes[1];
    const int* row = eidx;
    const int* col = eidx + E;

    const size_t MAT = (size_t)NN * NN;
    unsigned short* Abf  = (unsigned short*)d_ws;            // 128 MB
    unsigned short* A2bf = Abf + MAT;                        // 128 MB
    float*    deg    = (float*)(A2bf + MAT);                 // 32 KB
    int*      cnt    = (int*)(deg + NN);                     // 32 KB
    int*      rowptr = cnt + NN;                             // (NN+2)*4
    int*      cursor = rowptr + NN + 2;                      // 32 KB
    unsigned* epk    = (unsigned*)(cursor + NN);             // E*4 B

    size_t need = MAT * 2 * sizeof(unsigned short)
                + (size_t)(NN * 4 + 2) * sizeof(int)
                + (size_t)E * sizeof(unsigned);
    if (ws_size < need) return;

    float* Af = (float*)d_out;     // f32 A staging in d_out (dead after convert)
    float* P  = (float*)d_out;     // final output overwrites it

    hipMemsetAsync(d_out, 0, MAT * sizeof(float), stream);
    hipMemsetAsync(deg, 0, NN * sizeof(float), stream);
    hipMemsetAsync(cnt, 0, NN * sizeof(int), stream);

    int eb = (E + 255) / 256;
    deg_count_kernel<<<eb, 256, 0, stream>>>(row, col, deg, cnt, E);
    scan_kernel<<<1, 256, 0, stream>>>(cnt, rowptr, cursor);
    fill_kernel<<<eb, 256, 0, stream>>>(row, col, attr, deg, cursor, epk, Af, E);
    convert_kernel<<<(int)(MAT / 1024), 256, 0, stream>>>(Af, Abf);

    const int SPMM_BLOCKS = 2048 * 64;   // (NN/4 row groups) x 64 slabs
    spmm_kernel<0><<<SPMM_BLOCKS, 256, 0, stream>>>(rowptr, epk, Abf, A2bf, nullptr, nullptr, nullptr);
    spmm_kernel<1><<<SPMM_BLOCKS, 256, 0, stream>>>(rowptr, epk, A2bf, nullptr, P, Abf, A2bf);
}